// Round 11
// baseline (79.026 us; speedup 1.0000x reference)
//
#include <hip/hip_runtime.h>

#define BS 256

__device__ __forceinline__ float fast_tanh(float x) {
  // tanh(x) = 1 - 2/(exp2(x*2*log2e)+1); exact saturation via rcp(inf)=0
  float t = __builtin_amdgcn_exp2f(x * 2.8853900817779268f);
  return 1.0f - 2.0f * __builtin_amdgcn_rcpf(t + 1.0f);
}
__device__ __forceinline__ float fast_sigmoid(float x) {
  return __builtin_amdgcn_rcpf(1.0f + __builtin_amdgcn_exp2f(x * -1.4426950408889634f));
}

// nested-fma dot products; weight indices are compile-time literals -> uniform
// SGPR loads off the VALU pipe (r3-proven: VGPR=20, zero scratch).
#define D4(W, B, O, p0, p1, p2, p3)                                            \
  fmaf((W)[(O)*4 + 0], p0,                                                     \
  fmaf((W)[(O)*4 + 1], p1,                                                     \
  fmaf((W)[(O)*4 + 2], p2,                                                     \
  fmaf((W)[(O)*4 + 3], p3, (B)[O]))))

#define D8(W, B, O, p0, p1, p2, p3, p4, p5, p6, p7)                            \
  fmaf((W)[(O)*8 + 0], p0,                                                     \
  fmaf((W)[(O)*8 + 1], p1,                                                     \
  fmaf((W)[(O)*8 + 2], p2,                                                     \
  fmaf((W)[(O)*8 + 3], p3,                                                     \
  fmaf((W)[(O)*8 + 4], p4,                                                     \
  fmaf((W)[(O)*8 + 5], p5,                                                     \
  fmaf((W)[(O)*8 + 6], p6,                                                     \
  fmaf((W)[(O)*8 + 7], p7, (B)[O]))))))))

#define D12(W, B, O, p0, p1, p2, p3, p4, p5, p6, p7, p8, p9, pa, pb)           \
  fmaf((W)[(O)*12 + 0], p0,                                                    \
  fmaf((W)[(O)*12 + 1], p1,                                                    \
  fmaf((W)[(O)*12 + 2], p2,                                                    \
  fmaf((W)[(O)*12 + 3], p3,                                                    \
  fmaf((W)[(O)*12 + 4], p4,                                                    \
  fmaf((W)[(O)*12 + 5], p5,                                                    \
  fmaf((W)[(O)*12 + 6], p6,                                                    \
  fmaf((W)[(O)*12 + 7], p7,                                                    \
  fmaf((W)[(O)*12 + 8], p8,                                                    \
  fmaf((W)[(O)*12 + 9], p9,                                                    \
  fmaf((W)[(O)*12 +10], pa,                                                    \
  fmaf((W)[(O)*12 +11], pb, (B)[O]))))))))))))

#define D16(W, B, O, p0, p1, p2, p3, p4, p5, p6, p7, p8, p9, pa, pb, pc, pd, pe, pf) \
  fmaf((W)[(O)*16 + 0], p0,                                                    \
  fmaf((W)[(O)*16 + 1], p1,                                                    \
  fmaf((W)[(O)*16 + 2], p2,                                                    \
  fmaf((W)[(O)*16 + 3], p3,                                                    \
  fmaf((W)[(O)*16 + 4], p4,                                                    \
  fmaf((W)[(O)*16 + 5], p5,                                                    \
  fmaf((W)[(O)*16 + 6], p6,                                                    \
  fmaf((W)[(O)*16 + 7], p7,                                                    \
  fmaf((W)[(O)*16 + 8], p8,                                                    \
  fmaf((W)[(O)*16 + 9], p9,                                                    \
  fmaf((W)[(O)*16 +10], pa,                                                    \
  fmaf((W)[(O)*16 +11], pb,                                                    \
  fmaf((W)[(O)*16 +12], pc,                                                    \
  fmaf((W)[(O)*16 +13], pd,                                                    \
  fmaf((W)[(O)*16 +14], pe,                                                    \
  fmaf((W)[(O)*16 +15], pf, (B)[O]))))))))))))))))

// one full row, all named scalars (r3-proven body). forceinline'd twice into
// a single branch-free basic block -> scheduler interleaves the two streams.
__device__ __forceinline__ float process_row(
    float x0, float x1, float x2, float x3,
    float x4, float x5, float x6, float x7,
    const float* __restrict__ fm_w,  const float* __restrict__ fm_b,
    const float* __restrict__ c1_w,  const float* __restrict__ c1_b,
    const float* __restrict__ p1_w,  const float* __restrict__ p1_b,
    const float* __restrict__ c2_w,  const float* __restrict__ c2_b,
    const float* __restrict__ p2_w,  const float* __restrict__ p2_b,
    const float* __restrict__ c3_w,  const float* __restrict__ c3_b,
    const float* __restrict__ v_w,   const float* __restrict__ v_b,
    const float* __restrict__ o_w,   const float* __restrict__ o_b,
    const float* __restrict__ ln1_w, const float* __restrict__ ln1_b,
    const float* __restrict__ ln2_w, const float* __restrict__ ln2_b,
    const float* __restrict__ ffn1_w, const float* __restrict__ ffn1_b,
    const float* __restrict__ ffn2_w, const float* __restrict__ ffn2_b,
    const float* __restrict__ fs_w,  const float* __restrict__ fs_b,
    const float* __restrict__ head_w, const float* __restrict__ head_b) {
  // ---- fm: 8 -> 16, tanh ----
#define LFM(O) fast_tanh(D8(fm_w, fm_b, O, x0, x1, x2, x3, x4, x5, x6, x7))
  float a0 = LFM(0),  a1 = LFM(1),  a2 = LFM(2),  a3 = LFM(3);
  float a4 = LFM(4),  a5 = LFM(5),  a6 = LFM(6),  a7 = LFM(7);
  float a8 = LFM(8),  a9 = LFM(9),  aa = LFM(10), ab = LFM(11);
  float ac = LFM(12), ad = LFM(13), ae = LFM(14), af = LFM(15);
#undef LFM

  // ---- c1: 16 -> 16, tanh ----
#define LC1(O) fast_tanh(D16(c1_w, c1_b, O, a0,a1,a2,a3,a4,a5,a6,a7,a8,a9,aa,ab,ac,ad,ae,af))
  float b0 = LC1(0),  b1 = LC1(1),  b2 = LC1(2),  b3 = LC1(3);
  float b4 = LC1(4),  b5 = LC1(5),  b6 = LC1(6),  b7 = LC1(7);
  float b8 = LC1(8),  b9 = LC1(9),  ba = LC1(10), bb = LC1(11);
  float bc = LC1(12), bd = LC1(13), be = LC1(14), bf = LC1(15);
#undef LC1

  // ---- p1: 16 -> 12, tanh ----
#define LP1(O) fast_tanh(D16(p1_w, p1_b, O, b0,b1,b2,b3,b4,b5,b6,b7,b8,b9,ba,bb,bc,bd,be,bf))
  float c0 = LP1(0),  c1 = LP1(1),  c2 = LP1(2),  c3 = LP1(3);
  float c4 = LP1(4),  c5 = LP1(5),  c6 = LP1(6),  c7 = LP1(7);
  float c8 = LP1(8),  c9 = LP1(9),  ca = LP1(10), cb = LP1(11);
#undef LP1

  // ---- c2: 12 -> 8, tanh ----
#define LC2(O) fast_tanh(D12(c2_w, c2_b, O, c0,c1,c2,c3,c4,c5,c6,c7,c8,c9,ca,cb))
  float d0 = LC2(0), d1 = LC2(1), d2 = LC2(2), d3 = LC2(3);
  float d4 = LC2(4), d5 = LC2(5), d6 = LC2(6), d7 = LC2(7);
#undef LC2

  // ---- p2: 8 -> 4, tanh ----
#define LP2(O) fast_tanh(D8(p2_w, p2_b, O, d0, d1, d2, d3, d4, d5, d6, d7))
  float e0 = LP2(0), e1 = LP2(1), e2 = LP2(2), e3 = LP2(3);
#undef LP2

  // ---- c3: 4 -> 4, tanh  (xs) ----
  float s0 = fast_tanh(D4(c3_w, c3_b, 0, e0, e1, e2, e3));
  float s1 = fast_tanh(D4(c3_w, c3_b, 1, e0, e1, e2, e3));
  float s2 = fast_tanh(D4(c3_w, c3_b, 2, e0, e1, e2, e3));
  float s3 = fast_tanh(D4(c3_w, c3_b, 3, e0, e1, e2, e3));

  // ---- attention, seq len 1: softmax == 1 -> out == v; attn_out = o(v(xs)) ----
  float v0 = D4(v_w, v_b, 0, s0, s1, s2, s3);
  float v1 = D4(v_w, v_b, 1, s0, s1, s2, s3);
  float v2 = D4(v_w, v_b, 2, s0, s1, s2, s3);
  float v3 = D4(v_w, v_b, 3, s0, s1, s2, s3);
  float o0 = D4(o_w, o_b, 0, v0, v1, v2, v3);
  float o1 = D4(o_w, o_b, 1, v0, v1, v2, v3);
  float o2 = D4(o_w, o_b, 2, v0, v1, v2, v3);
  float o3 = D4(o_w, o_b, 3, v0, v1, v2, v3);

  // ---- residual + LN1 ----
  float t0 = s0 + o0, t1 = s1 + o1, t2 = s2 + o2, t3 = s3 + o3;
  float mu = (t0 + t1 + t2 + t3) * 0.25f;
  float q0 = t0 - mu, q1 = t1 - mu, q2 = t2 - mu, q3 = t3 - mu;
  float var = (q0 * q0 + q1 * q1 + q2 * q2 + q3 * q3) * 0.25f;
  float inv = __builtin_amdgcn_rsqf(var + 1e-5f);
  float n0 = q0 * inv * ln1_w[0] + ln1_b[0];
  float n1 = q1 * inv * ln1_w[1] + ln1_b[1];
  float n2 = q2 * inv * ln1_w[2] + ln1_b[2];
  float n3 = q3 * inv * ln1_w[3] + ln1_b[3];

  // ---- FFN: relu(4->8) -> 8->4 ----
#define LF1(O) fmaxf(D4(ffn1_w, ffn1_b, O, n0, n1, n2, n3), 0.0f)
  float f0 = LF1(0), f1 = LF1(1), f2 = LF1(2), f3 = LF1(3);
  float f4 = LF1(4), f5 = LF1(5), f6 = LF1(6), f7 = LF1(7);
#undef LF1
  float g0 = D8(ffn2_w, ffn2_b, 0, f0, f1, f2, f3, f4, f5, f6, f7);
  float g1 = D8(ffn2_w, ffn2_b, 1, f0, f1, f2, f3, f4, f5, f6, f7);
  float g2 = D8(ffn2_w, ffn2_b, 2, f0, f1, f2, f3, f4, f5, f6, f7);
  float g3 = D8(ffn2_w, ffn2_b, 3, f0, f1, f2, f3, f4, f5, f6, f7);

  // ---- residual + LN2 ----
  float u0 = n0 + g0, u1 = n1 + g1, u2 = n2 + g2, u3 = n3 + g3;
  float mu2 = (u0 + u1 + u2 + u3) * 0.25f;
  float r0 = u0 - mu2, r1 = u1 - mu2, r2 = u2 - mu2, r3 = u3 - mu2;
  float var2 = (r0 * r0 + r1 * r1 + r2 * r2 + r3 * r3) * 0.25f;
  float inv2 = __builtin_amdgcn_rsqf(var2 + 1e-5f);
  float m0 = r0 * inv2 * ln2_w[0] + ln2_b[0];
  float m1 = r1 * inv2 * ln2_w[1] + ln2_b[1];
  float m2 = r2 * inv2 * ln2_w[2] + ln2_b[2];
  float m3 = r3 * inv2 * ln2_w[3] + ln2_b[3];

  // ---- final scale: tanh(fs)*1.5+0.2, head, sigmoid ----
  float h0 = fast_tanh(D4(fs_w, fs_b, 0, m0, m1, m2, m3)) * 1.5f + 0.2f;
  float h1 = fast_tanh(D4(fs_w, fs_b, 1, m0, m1, m2, m3)) * 1.5f + 0.2f;
  float h2 = fast_tanh(D4(fs_w, fs_b, 2, m0, m1, m2, m3)) * 1.5f + 0.2f;
  float h3 = fast_tanh(D4(fs_w, fs_b, 3, m0, m1, m2, m3)) * 1.5f + 0.2f;
  float y = fmaf(head_w[3], h3,
            fmaf(head_w[2], h2,
            fmaf(head_w[1], h1,
            fmaf(head_w[0], h0, head_b[0]))));
  return fast_sigmoid(y);
}

#define WARGS fm_w, fm_b, c1_w, c1_b, p1_w, p1_b, c2_w, c2_b, p2_w, p2_b,      \
              c3_w, c3_b, v_w, v_b, o_w, o_b, ln1_w, ln1_b, ln2_w, ln2_b,      \
              ffn1_w, ffn1_b, ffn2_w, ffn2_b, fs_w, fs_b, head_w, head_b

__global__ void __launch_bounds__(BS) qcnn_2s(
    const float* __restrict__ inp,
    const float* __restrict__ fm_w,  const float* __restrict__ fm_b,
    const float* __restrict__ c1_w,  const float* __restrict__ c1_b,
    const float* __restrict__ p1_w,  const float* __restrict__ p1_b,
    const float* __restrict__ c2_w,  const float* __restrict__ c2_b,
    const float* __restrict__ p2_w,  const float* __restrict__ p2_b,
    const float* __restrict__ c3_w,  const float* __restrict__ c3_b,
    const float* __restrict__ v_w,   const float* __restrict__ v_b,
    const float* __restrict__ o_w,   const float* __restrict__ o_b,
    const float* __restrict__ ln1_w, const float* __restrict__ ln1_b,
    const float* __restrict__ ln2_w, const float* __restrict__ ln2_b,
    const float* __restrict__ ffn1_w, const float* __restrict__ ffn1_b,
    const float* __restrict__ ffn2_w, const float* __restrict__ ffn2_b,
    const float* __restrict__ fs_w,  const float* __restrict__ fs_b,
    const float* __restrict__ head_w, const float* __restrict__ head_b,
    float* __restrict__ out) {
  // exact grid: nrows = 2^21, 2 rows/thread, 4096 blocks x 256 threads.
  const long long gid = (long long)blockIdx.x * BS + threadIdx.x;

  // two adjacent rows: 16 contiguous floats = 4 float4 loads, no tail.
  const float4* __restrict__ in4 = reinterpret_cast<const float4*>(inp);
  float4 p0 = in4[gid * 4 + 0];
  float4 p1 = in4[gid * 4 + 1];
  float4 p2 = in4[gid * 4 + 2];
  float4 p3 = in4[gid * 4 + 3];

  float y0 = process_row(p0.x, p0.y, p0.z, p0.w, p1.x, p1.y, p1.z, p1.w, WARGS);
  float y1 = process_row(p2.x, p2.y, p2.z, p2.w, p3.x, p3.y, p3.z, p3.w, WARGS);

  reinterpret_cast<float2*>(out)[gid] = make_float2(y0, y1);
}

extern "C" void kernel_launch(void* const* d_in, const int* in_sizes, int n_in,
                              void* d_out, int out_size, void* d_ws, size_t ws_size,
                              hipStream_t stream) {
  const float* inp = (const float*)d_in[0];
  long long nrows = (long long)in_sizes[0] / 8;          // 2097152
  long long nthreads = nrows / 2;                        // exact (B = 2^21)
  dim3 grid((unsigned)(nthreads / BS)), block(BS);       // 4096 x 256 exact
  qcnn_2s<<<grid, block, 0, stream>>>(
      inp,
      (const float*)d_in[1],  (const float*)d_in[2],   // fm
      (const float*)d_in[3],  (const float*)d_in[4],   // c1
      (const float*)d_in[5],  (const float*)d_in[6],   // p1
      (const float*)d_in[7],  (const float*)d_in[8],   // c2
      (const float*)d_in[9],  (const float*)d_in[10],  // p2
      (const float*)d_in[11], (const float*)d_in[12],  // c3
      (const float*)d_in[17], (const float*)d_in[18],  // v (q/k dead: softmax over len-1 == 1)
      (const float*)d_in[19], (const float*)d_in[20],  // o
      (const float*)d_in[21], (const float*)d_in[22],  // ln1
      (const float*)d_in[23], (const float*)d_in[24],  // ln2
      (const float*)d_in[25], (const float*)d_in[26],  // ffn1
      (const float*)d_in[27], (const float*)d_in[28],  // ffn2
      (const float*)d_in[29], (const float*)d_in[30],  // fs
      (const float*)d_in[31], (const float*)d_in[32],  // head
      (float*)d_out);
}

// Round 12
// 59.414 us; speedup vs baseline: 1.3301x; 1.3301x over previous
//
#include <hip/hip_runtime.h>

#define BS 256

typedef float f32x2 __attribute__((ext_vector_type(2)));

__device__ __forceinline__ f32x2 splat2(float v) {
  f32x2 r; r[0] = v; r[1] = v; return r;
}
// packed fma: d = w*x + a, w wave-uniform scalar
__device__ __forceinline__ f32x2 pkfma(float w, f32x2 x, f32x2 a) {
  return __builtin_elementwise_fma(splat2(w), x, a);
}

__device__ __forceinline__ f32x2 fast_tanh2(f32x2 x) {
  // tanh(x) = 1 - 2/(exp2(x*2*log2e)+1); exact saturation via rcp(inf)=0
  f32x2 z = x * 2.8853900817779268f;
  f32x2 t;
  t[0] = __builtin_amdgcn_exp2f(z[0]);
  t[1] = __builtin_amdgcn_exp2f(z[1]);
  f32x2 tp1 = t + 1.0f;
  f32x2 r;
  r[0] = __builtin_amdgcn_rcpf(tp1[0]);
  r[1] = __builtin_amdgcn_rcpf(tp1[1]);
  return __builtin_elementwise_fma(splat2(-2.0f), r, splat2(1.0f));
}
__device__ __forceinline__ f32x2 fast_sigmoid2(f32x2 x) {
  f32x2 z = x * -1.4426950408889634f;
  f32x2 t;
  t[0] = __builtin_amdgcn_exp2f(z[0]);
  t[1] = __builtin_amdgcn_exp2f(z[1]);
  f32x2 tp1 = t + 1.0f;
  f32x2 r;
  r[0] = __builtin_amdgcn_rcpf(tp1[0]);
  r[1] = __builtin_amdgcn_rcpf(tp1[1]);
  return r;
}
__device__ __forceinline__ f32x2 relu2(f32x2 x) {
  return __builtin_elementwise_max(x, splat2(0.0f));
}

// nested packed-fma dot products; weight indices are literals -> uniform s_loads
#define D4(W, B, O, p0, p1, p2, p3)                                            \
  pkfma((W)[(O)*4 + 0], p0,                                                    \
  pkfma((W)[(O)*4 + 1], p1,                                                    \
  pkfma((W)[(O)*4 + 2], p2,                                                    \
  pkfma((W)[(O)*4 + 3], p3, splat2((B)[O])))))

#define D8(W, B, O, p0, p1, p2, p3, p4, p5, p6, p7)                            \
  pkfma((W)[(O)*8 + 0], p0,                                                    \
  pkfma((W)[(O)*8 + 1], p1,                                                    \
  pkfma((W)[(O)*8 + 2], p2,                                                    \
  pkfma((W)[(O)*8 + 3], p3,                                                    \
  pkfma((W)[(O)*8 + 4], p4,                                                    \
  pkfma((W)[(O)*8 + 5], p5,                                                    \
  pkfma((W)[(O)*8 + 6], p6,                                                    \
  pkfma((W)[(O)*8 + 7], p7, splat2((B)[O])))))))))

#define D12(W, B, O, p0, p1, p2, p3, p4, p5, p6, p7, p8, p9, pa, pb)           \
  pkfma((W)[(O)*12 + 0], p0,                                                   \
  pkfma((W)[(O)*12 + 1], p1,                                                   \
  pkfma((W)[(O)*12 + 2], p2,                                                   \
  pkfma((W)[(O)*12 + 3], p3,                                                   \
  pkfma((W)[(O)*12 + 4], p4,                                                   \
  pkfma((W)[(O)*12 + 5], p5,                                                   \
  pkfma((W)[(O)*12 + 6], p6,                                                   \
  pkfma((W)[(O)*12 + 7], p7,                                                   \
  pkfma((W)[(O)*12 + 8], p8,                                                   \
  pkfma((W)[(O)*12 + 9], p9,                                                   \
  pkfma((W)[(O)*12 +10], pa,                                                   \
  pkfma((W)[(O)*12 +11], pb, splat2((B)[O])))))))))))))

#define D16(W, B, O, p0, p1, p2, p3, p4, p5, p6, p7, p8, p9, pa, pb, pc, pd, pe, pf) \
  pkfma((W)[(O)*16 + 0], p0,                                                   \
  pkfma((W)[(O)*16 + 1], p1,                                                   \
  pkfma((W)[(O)*16 + 2], p2,                                                   \
  pkfma((W)[(O)*16 + 3], p3,                                                   \
  pkfma((W)[(O)*16 + 4], p4,                                                   \
  pkfma((W)[(O)*16 + 5], p5,                                                   \
  pkfma((W)[(O)*16 + 6], p6,                                                   \
  pkfma((W)[(O)*16 + 7], p7,                                                   \
  pkfma((W)[(O)*16 + 8], p8,                                                   \
  pkfma((W)[(O)*16 + 9], p9,                                                   \
  pkfma((W)[(O)*16 +10], pa,                                                   \
  pkfma((W)[(O)*16 +11], pb,                                                   \
  pkfma((W)[(O)*16 +12], pc,                                                   \
  pkfma((W)[(O)*16 +13], pd,                                                   \
  pkfma((W)[(O)*16 +14], pe,                                                   \
  pkfma((W)[(O)*16 +15], pf, splat2((B)[O])))))))))))))))))

__global__ void __launch_bounds__(BS, 8) qcnn_pk2(
    const float* __restrict__ inp,
    const float* __restrict__ fm_w,  const float* __restrict__ fm_b,
    const float* __restrict__ c1_w,  const float* __restrict__ c1_b,
    const float* __restrict__ p1_w,  const float* __restrict__ p1_b,
    const float* __restrict__ c2_w,  const float* __restrict__ c2_b,
    const float* __restrict__ p2_w,  const float* __restrict__ p2_b,
    const float* __restrict__ c3_w,  const float* __restrict__ c3_b,
    const float* __restrict__ v_w,   const float* __restrict__ v_b,
    const float* __restrict__ o_w,   const float* __restrict__ o_b,
    const float* __restrict__ ln1_w, const float* __restrict__ ln1_b,
    const float* __restrict__ ln2_w, const float* __restrict__ ln2_b,
    const float* __restrict__ ffn1_w, const float* __restrict__ ffn1_b,
    const float* __restrict__ ffn2_w, const float* __restrict__ ffn2_b,
    const float* __restrict__ fs_w,  const float* __restrict__ fs_b,
    const float* __restrict__ head_w, const float* __restrict__ head_b,
    float* __restrict__ out) {
  // exact grid: 2^21 rows = 4096 blocks x 256 threads x 2 rows. No tail.
  const long long gid = (long long)blockIdx.x * BS + threadIdx.x;

  // ---- input: 2 rows x 8 floats = 4 float4 loads (64B/lane, coalesced) ----
  const float4* __restrict__ in4 = reinterpret_cast<const float4*>(inp);
  float4 r0lo = in4[gid * 4 + 0];
  float4 r0hi = in4[gid * 4 + 1];
  float4 r1lo = in4[gid * 4 + 2];
  float4 r1hi = in4[gid * 4 + 3];
  f32x2 x0 = {r0lo.x, r1lo.x}, x1 = {r0lo.y, r1lo.y};
  f32x2 x2 = {r0lo.z, r1lo.z}, x3 = {r0lo.w, r1lo.w};
  f32x2 x4 = {r0hi.x, r1hi.x}, x5 = {r0hi.y, r1hi.y};
  f32x2 x6 = {r0hi.z, r1hi.z}, x7 = {r0hi.w, r1hi.w};

  // ---- fm: 8 -> 16, tanh ----
#define LFM(O) fast_tanh2(D8(fm_w, fm_b, O, x0, x1, x2, x3, x4, x5, x6, x7))
  f32x2 a0 = LFM(0),  a1 = LFM(1),  a2 = LFM(2),  a3 = LFM(3);
  f32x2 a4 = LFM(4),  a5 = LFM(5),  a6 = LFM(6),  a7 = LFM(7);
  f32x2 a8 = LFM(8),  a9 = LFM(9),  aa = LFM(10), ab = LFM(11);
  f32x2 ac = LFM(12), ad = LFM(13), ae = LFM(14), af = LFM(15);

  // ---- c1: 16 -> 16, tanh ----
#define LC1(O) fast_tanh2(D16(c1_w, c1_b, O, a0,a1,a2,a3,a4,a5,a6,a7,a8,a9,aa,ab,ac,ad,ae,af))
  f32x2 b0 = LC1(0),  b1 = LC1(1),  b2 = LC1(2),  b3 = LC1(3);
  f32x2 b4 = LC1(4),  b5 = LC1(5),  b6 = LC1(6),  b7 = LC1(7);
  f32x2 b8 = LC1(8),  b9 = LC1(9),  ba = LC1(10), bb = LC1(11);
  f32x2 bc = LC1(12), bd = LC1(13), be = LC1(14), bf = LC1(15);

  // ---- p1: 16 -> 12, tanh ----
#define LP1(O) fast_tanh2(D16(p1_w, p1_b, O, b0,b1,b2,b3,b4,b5,b6,b7,b8,b9,ba,bb,bc,bd,be,bf))
  f32x2 c0 = LP1(0),  c1 = LP1(1),  c2 = LP1(2),  c3 = LP1(3);
  f32x2 c4 = LP1(4),  c5 = LP1(5),  c6 = LP1(6),  c7 = LP1(7);
  f32x2 c8 = LP1(8),  c9 = LP1(9),  ca = LP1(10), cb = LP1(11);

  // ---- c2: 12 -> 8, tanh ----
#define LC2(O) fast_tanh2(D12(c2_w, c2_b, O, c0,c1,c2,c3,c4,c5,c6,c7,c8,c9,ca,cb))
  f32x2 d0 = LC2(0), d1 = LC2(1), d2 = LC2(2), d3 = LC2(3);
  f32x2 d4 = LC2(4), d5 = LC2(5), d6 = LC2(6), d7 = LC2(7);

  // ---- p2: 8 -> 4, tanh ----
#define LP2(O) fast_tanh2(D8(p2_w, p2_b, O, d0, d1, d2, d3, d4, d5, d6, d7))
  f32x2 e0 = LP2(0), e1 = LP2(1), e2 = LP2(2), e3 = LP2(3);

  // ---- c3: 4 -> 4, tanh  (xs) ----
  f32x2 s0 = fast_tanh2(D4(c3_w, c3_b, 0, e0, e1, e2, e3));
  f32x2 s1 = fast_tanh2(D4(c3_w, c3_b, 1, e0, e1, e2, e3));
  f32x2 s2 = fast_tanh2(D4(c3_w, c3_b, 2, e0, e1, e2, e3));
  f32x2 s3 = fast_tanh2(D4(c3_w, c3_b, 3, e0, e1, e2, e3));

  // ---- attention, seq len 1: softmax == 1 -> out == v; attn_out = o(v(xs)) ----
  f32x2 v0 = D4(v_w, v_b, 0, s0, s1, s2, s3);
  f32x2 v1 = D4(v_w, v_b, 1, s0, s1, s2, s3);
  f32x2 v2 = D4(v_w, v_b, 2, s0, s1, s2, s3);
  f32x2 v3 = D4(v_w, v_b, 3, s0, s1, s2, s3);
  f32x2 o0 = D4(o_w, o_b, 0, v0, v1, v2, v3);
  f32x2 o1 = D4(o_w, o_b, 1, v0, v1, v2, v3);
  f32x2 o2 = D4(o_w, o_b, 2, v0, v1, v2, v3);
  f32x2 o3 = D4(o_w, o_b, 3, v0, v1, v2, v3);

  // ---- residual + LN1 (all packed) ----
  f32x2 t0 = s0 + o0, t1 = s1 + o1, t2 = s2 + o2, t3 = s3 + o3;
  f32x2 mu = (t0 + t1 + t2 + t3) * 0.25f;
  f32x2 q0 = t0 - mu, q1 = t1 - mu, q2 = t2 - mu, q3 = t3 - mu;
  f32x2 var = (q0 * q0 + q1 * q1 + q2 * q2 + q3 * q3) * 0.25f + 1e-5f;
  f32x2 inv;
  inv[0] = __builtin_amdgcn_rsqf(var[0]);
  inv[1] = __builtin_amdgcn_rsqf(var[1]);
  f32x2 n0 = q0 * inv * ln1_w[0] + ln1_b[0];
  f32x2 n1 = q1 * inv * ln1_w[1] + ln1_b[1];
  f32x2 n2 = q2 * inv * ln1_w[2] + ln1_b[2];
  f32x2 n3 = q3 * inv * ln1_w[3] + ln1_b[3];

  // ---- FFN: relu(4->8) -> 8->4 ----
#define LF1(O) relu2(D4(ffn1_w, ffn1_b, O, n0, n1, n2, n3))
  f32x2 f0 = LF1(0), f1 = LF1(1), f2 = LF1(2), f3 = LF1(3);
  f32x2 f4 = LF1(4), f5 = LF1(5), f6 = LF1(6), f7 = LF1(7);
  f32x2 g0 = D8(ffn2_w, ffn2_b, 0, f0, f1, f2, f3, f4, f5, f6, f7);
  f32x2 g1 = D8(ffn2_w, ffn2_b, 1, f0, f1, f2, f3, f4, f5, f6, f7);
  f32x2 g2 = D8(ffn2_w, ffn2_b, 2, f0, f1, f2, f3, f4, f5, f6, f7);
  f32x2 g3 = D8(ffn2_w, ffn2_b, 3, f0, f1, f2, f3, f4, f5, f6, f7);

  // ---- residual + LN2 ----
  f32x2 u0 = n0 + g0, u1 = n1 + g1, u2 = n2 + g2, u3 = n3 + g3;
  f32x2 mu2 = (u0 + u1 + u2 + u3) * 0.25f;
  f32x2 w0 = u0 - mu2, w1 = u1 - mu2, w2 = u2 - mu2, w3 = u3 - mu2;
  f32x2 var2 = (w0 * w0 + w1 * w1 + w2 * w2 + w3 * w3) * 0.25f + 1e-5f;
  f32x2 inv2;
  inv2[0] = __builtin_amdgcn_rsqf(var2[0]);
  inv2[1] = __builtin_amdgcn_rsqf(var2[1]);
  f32x2 m0 = w0 * inv2 * ln2_w[0] + ln2_b[0];
  f32x2 m1 = w1 * inv2 * ln2_w[1] + ln2_b[1];
  f32x2 m2 = w2 * inv2 * ln2_w[2] + ln2_b[2];
  f32x2 m3 = w3 * inv2 * ln2_w[3] + ln2_b[3];

  // ---- final scale: tanh(fs)*1.5+0.2, head, sigmoid ----
  f32x2 h0 = fast_tanh2(D4(fs_w, fs_b, 0, m0, m1, m2, m3)) * 1.5f + 0.2f;
  f32x2 h1 = fast_tanh2(D4(fs_w, fs_b, 1, m0, m1, m2, m3)) * 1.5f + 0.2f;
  f32x2 h2 = fast_tanh2(D4(fs_w, fs_b, 2, m0, m1, m2, m3)) * 1.5f + 0.2f;
  f32x2 h3 = fast_tanh2(D4(fs_w, fs_b, 3, m0, m1, m2, m3)) * 1.5f + 0.2f;
  f32x2 y = pkfma(head_w[3], h3,
            pkfma(head_w[2], h2,
            pkfma(head_w[1], h1,
            pkfma(head_w[0], h0, splat2(head_b[0])))));
  y = fast_sigmoid2(y);

  reinterpret_cast<float2*>(out)[gid] = make_float2(y[0], y[1]);
}

extern "C" void kernel_launch(void* const* d_in, const int* in_sizes, int n_in,
                              void* d_out, int out_size, void* d_ws, size_t ws_size,
                              hipStream_t stream) {
  const float* inp = (const float*)d_in[0];
  long long nrows = (long long)in_sizes[0] / 8;          // 2097152 = 2^21
  long long nthreads = nrows / 2;                        // exact
  dim3 grid((unsigned)(nthreads / BS)), block(BS);       // 4096 x 256 exact
  qcnn_pk2<<<grid, block, 0, stream>>>(
      inp,
      (const float*)d_in[1],  (const float*)d_in[2],   // fm
      (const float*)d_in[3],  (const float*)d_in[4],   // c1
      (const float*)d_in[5],  (const float*)d_in[6],   // p1
      (const float*)d_in[7],  (const float*)d_in[8],   // c2
      (const float*)d_in[9],  (const float*)d_in[10],  // p2
      (const float*)d_in[11], (const float*)d_in[12],  // c3
      (const float*)d_in[17], (const float*)d_in[18],  // v (q/k dead: softmax over len-1 == 1)
      (const float*)d_in[19], (const float*)d_in[20],  // o
      (const float*)d_in[21], (const float*)d_in[22],  // ln1
      (const float*)d_in[23], (const float*)d_in[24],  // ln2
      (const float*)d_in[25], (const float*)d_in[26],  // ffn1
      (const float*)d_in[27], (const float*)d_in[28],  // ffn2
      (const float*)d_in[29], (const float*)d_in[30],  // fs
      (const float*)d_in[31], (const float*)d_in[32],  // head
      (float*)d_out);
}